// Round 1
// baseline (252.240 us; speedup 1.0000x reference)
//
#include <hip/hip_runtime.h>

#define B_ROWS 16384
#define D_IN   1024
#define H_DIM  256
#define N_EXP  8
#define N_TASK 4
#define NKT    16   // K-tiles of 64 in D_IN

typedef short bf16x8 __attribute__((ext_vector_type(8)));
typedef float f32x4  __attribute__((ext_vector_type(4)));

static __device__ __forceinline__ unsigned short f2bf(float f) {
  unsigned int u = __float_as_uint(f);
  u += 0x7fffu + ((u >> 16) & 1u);   // RNE
  return (unsigned short)(u >> 16);
}
static __device__ __forceinline__ float bf2f(unsigned short u) {
  return __uint_as_float(((unsigned int)u) << 16);
}

// workspace layout (bytes)
#define WS_XB   0u          // ushort[16384*1024]  = 33,554,432 B
#define WS_WET  33554432u   // ushort[8*256*1024]  =  4,194,304 B
#define WS_WGT  37748736u   // ushort[32*1024]     =     65,536 B
#define WS_G    37814272u   // float [16384*32]    =  2,097,152 B (logits -> probs in place)
#define WS_E    39911424u   // ushort[16384*2048]  = 67,108,864 B

// ---------------------------------------------------------------------------
// Kernel 1: cast+transpose We -> We_t[e][h][k] bf16 ; Wg -> Wg_t[n][k] bf16
// ---------------------------------------------------------------------------
__global__ void k_prep_w(const float* __restrict__ We, const float* __restrict__ Wg,
                         unsigned short* __restrict__ We_t, unsigned short* __restrict__ Wg_t) {
  int bid = blockIdx.x;
  int t = threadIdx.x;
  if (bid < 512) {
    // one 64x64 tile of We[e]: [k][h] -> [h][k]
    int e = bid >> 6;
    int tl = bid & 63;
    int k0 = (tl >> 2) * 64, h0 = (tl & 3) * 64;
    __shared__ unsigned short tile[64][72];   // [h][k], padded
    const float* src = We + (size_t)e * (D_IN * H_DIM);
#pragma unroll
    for (int i = 0; i < 4; ++i) {
      int kk = (t >> 4) + i * 16;
      int hh = (t & 15) * 4;
      float4 v = *(const float4*)(src + (size_t)(k0 + kk) * H_DIM + h0 + hh);
      tile[hh + 0][kk] = f2bf(v.x);
      tile[hh + 1][kk] = f2bf(v.y);
      tile[hh + 2][kk] = f2bf(v.z);
      tile[hh + 3][kk] = f2bf(v.w);
    }
    __syncthreads();
    unsigned short* dst = We_t + (size_t)e * (H_DIM * D_IN);
#pragma unroll
    for (int i = 0; i < 4; ++i) {
      int hh = (t >> 4) + i * 16;
      int kk = (t & 15) * 4;
      ushort4 u = *(const ushort4*)&tile[hh][kk];
      *(ushort4*)(dst + (size_t)(h0 + hh) * D_IN + k0 + kk) = u;
    }
  } else {
    // Wg[4][1024][8] -> Wg_t[n=t*8+e][k]
    int n = t & 31;
    int kbase = (t >> 5) * 128;
    int tsk = n >> 3, e = n & 7;
    for (int i = 0; i < 128; ++i) {
      int k = kbase + i;
      Wg_t[(size_t)n * D_IN + k] = f2bf(Wg[(size_t)tsk * (D_IN * 8) + (size_t)k * 8 + e]);
    }
  }
}

// ---------------------------------------------------------------------------
// Kernel 2: fused cast + gate logit partials, K-split, atomic accumulate.
// ---------------------------------------------------------------------------
__global__ void k_gates(const float* __restrict__ x,
                        const unsigned short* __restrict__ Wg_t,
                        unsigned short* __restrict__ x_b,
                        float* __restrict__ Glog) {
  __shared__ unsigned short xs[64][136];
  __shared__ unsigned short wgs[32][136];
  int m0 = blockIdx.x * 64;
  int ks = blockIdx.y;
  int kbase = ks * 256;
  int t = threadIdx.x;
  int wv = t >> 6, l = t & 63;
  f32x4 acc0 = {0.f, 0.f, 0.f, 0.f}, acc1 = {0.f, 0.f, 0.f, 0.f};

  for (int k0 = kbase; k0 < kbase + 256; k0 += 128) {
    {
      int r = t >> 2;
      int cb = (t & 3) * 32;
      const float* p = x + (size_t)(m0 + r) * D_IN + k0 + cb;
      unsigned short* q = x_b + (size_t)(m0 + r) * D_IN + k0 + cb;
#pragma unroll
      for (int i = 0; i < 8; ++i) {
        float4 v = *(const float4*)(p + i * 4);
        ushort4 u;
        u.x = f2bf(v.x); u.y = f2bf(v.y); u.z = f2bf(v.z); u.w = f2bf(v.w);
        *(ushort4*)&xs[r][cb + i * 4] = u;
        *(ushort4*)(q + i * 4) = u;
      }
    }
    {
      int n = t >> 3;
      int kk = (t & 7) * 16;
      const unsigned short* p = Wg_t + (size_t)n * D_IN + k0 + kk;
#pragma unroll
      for (int i = 0; i < 4; ++i)
        *(ushort4*)&wgs[n][kk + i * 4] = *(const ushort4*)(p + i * 4);
    }
    __syncthreads();
#pragma unroll
    for (int kk = 0; kk < 4; ++kk) {
      bf16x8 a  = *(const bf16x8*)&xs[wv * 16 + (l & 15)][kk * 32 + (l >> 4) * 8];
      bf16x8 b0 = *(const bf16x8*)&wgs[(l & 15)][kk * 32 + (l >> 4) * 8];
      bf16x8 b1 = *(const bf16x8*)&wgs[16 + (l & 15)][kk * 32 + (l >> 4) * 8];
      acc0 = __builtin_amdgcn_mfma_f32_16x16x32_bf16(a, b0, acc0, 0, 0, 0);
      acc1 = __builtin_amdgcn_mfma_f32_16x16x32_bf16(a, b1, acc1, 0, 0, 0);
    }
    __syncthreads();
  }
  int rbase = m0 + wv * 16 + (l >> 4) * 4;
  int col = l & 15;
#pragma unroll
  for (int j = 0; j < 4; ++j) {
    atomicAdd(&Glog[(size_t)(rbase + j) * 32 + col],      acc0[j]);
    atomicAdd(&Glog[(size_t)(rbase + j) * 32 + 16 + col], acc1[j]);
  }
}

// ---------------------------------------------------------------------------
// Kernel 3: expert GEMM — 256x256 tile, 8 waves (2Mx4N), BK=64, 4-phase
// pipelined K-loop with counted vmcnt (T3+T4), XOR-swizzled LDS (T2),
// setprio around MFMA (T5), XCD block swizzle (T1).
// blocks [0,512): E[b][e*256+h] = relu(x@We + be) -> bf16 ws
// blocks [512,544): softmax(Glog+bg) in place -> G probs (disjoint memory)
//
// Staging schedule (buffer c = kt&1):
//   phase 0: read all 8 B-frags of kt (regs, B region of buf c free after) +
//            A-frags fm=0,1 ; stage A-half0(kt+1) -> buf c^1
//   phase 1: A-frags fm=2,3 ; stage A-half1(kt+1) -> buf c^1
//   phase 2: A-frags fm=4,5 ; stage B-half0(kt+2) -> buf c   (B free since ph1)
//   phase 3: A-frags fm=6,7 ; stage B-half1(kt+2) -> buf c ;
//            s_waitcnt vmcnt(4)  (only B(kt+2) may stay in flight)
// Prologue stages kt0 fully + B(kt1); vmcnt(4) leaves B(kt1) in flight.
// Tail: entering last K-tile needs vmcnt(0) (its B halves are the newest 4).
// ---------------------------------------------------------------------------
__global__ __launch_bounds__(512, 2) void k_expert(const unsigned short* __restrict__ x_b,
                                                   const unsigned short* __restrict__ We_t,
                                                   const float* __restrict__ be,
                                                   const float* __restrict__ bg,
                                                   float* __restrict__ Glog,
                                                   unsigned short* __restrict__ E) {
  __shared__ unsigned short As[2][256 * 64];   // 64 KiB
  __shared__ unsigned short Bs[2][256 * 64];   // 64 KiB
  int bid = blockIdx.x;
  int t = threadIdx.x;

  if (bid >= 512) {
    // ---- gate finalize: 32 blocks x 512 threads = 16384 rows ----
    int row = (bid - 512) * 512 + t;
    float v[32];
#pragma unroll
    for (int c = 0; c < 8; ++c) {
      float4 a = *(const float4*)(Glog + (size_t)row * 32 + c * 4);
      v[c * 4 + 0] = a.x; v[c * 4 + 1] = a.y; v[c * 4 + 2] = a.z; v[c * 4 + 3] = a.w;
    }
#pragma unroll
    for (int n = 0; n < 32; ++n) v[n] += bg[n];
#pragma unroll
    for (int tk = 0; tk < 4; ++tk) {
      float mx = -1e30f;
#pragma unroll
      for (int e2 = 0; e2 < 8; ++e2) mx = fmaxf(mx, v[tk * 8 + e2]);
      float s = 0.f;
#pragma unroll
      for (int e2 = 0; e2 < 8; ++e2) { v[tk * 8 + e2] = __expf(v[tk * 8 + e2] - mx); s += v[tk * 8 + e2]; }
      float inv = 1.f / s;
#pragma unroll
      for (int e2 = 0; e2 < 8; ++e2) v[tk * 8 + e2] *= inv;
    }
#pragma unroll
    for (int c = 0; c < 8; ++c)
      *(float4*)(Glog + (size_t)row * 32 + c * 4) =
          make_float4(v[c * 4], v[c * 4 + 1], v[c * 4 + 2], v[c * 4 + 3]);
    return;
  }

  // ---- expert GEMM ----
  // XCD swizzle: 8 consecutive same-XCD slots share one m-tile's A panel
  int xcd = bid & 7;
  int idx = bid >> 3;              // 0..63
  int m   = xcd * 8 + (idx >> 3);  // m-tile 0..63
  int e   = idx & 7;
  int m0  = m * 256;

  int w  = t >> 6, l = t & 63;
  int wm = w >> 2, wn = w & 3;     // wave tile: rows wm*128..+128, cols wn*64..+64
  int lr = l & 15, lq = l >> 4;

  const unsigned short* Ab = x_b + (size_t)m0 * D_IN;
  const unsigned short* Bb = We_t + (size_t)e * (H_DIM * D_IN);

  const int sr = t >> 3, sg = t & 7;                 // staging row / 16B granule
  const int swz0 = ((lq ^ (lr & 7)) << 3);           // ks=0 swizzled granule (ushorts)
  const int swz1 = (((4 + lq) ^ (lr & 7)) << 3);     // ks=1
  const int arow0 = (wm * 128 + lr) << 6;            // + fm*1024
  const int brow0 = (wn * 64 + lr) << 6;             // + fn*1024

  f32x4 acc[8][4];
#pragma unroll
  for (int i = 0; i < 8; ++i)
#pragma unroll
    for (int j = 0; j < 4; ++j) acc[i][j] = (f32x4){0.f, 0.f, 0.f, 0.f};

  // half-tile = 128 rows x 64 k bf16 = 16 KiB = 2 load instrs (512 thr x 16 B)
  // dest is linear (base + t*16); source k-granule pre-swizzled (rule 21)
#define STAGE_A(cb, kt, h)                                                                       \
  do {                                                                                           \
    int r0_ = (h) * 128 + sr;                                                                    \
    int r1_ = r0_ + 64;                                                                          \
    __builtin_amdgcn_global_load_lds(                                                            \
        (const __attribute__((address_space(1))) void*)(Ab + (size_t)r0_ * D_IN + (kt) * 64 +    \
                                                        ((sg ^ (r0_ & 7)) << 3)),                \
        (__attribute__((address_space(3))) void*)(&As[(cb)][r0_ * 64 + sg * 8]), 16, 0, 0);      \
    __builtin_amdgcn_global_load_lds(                                                            \
        (const __attribute__((address_space(1))) void*)(Ab + (size_t)r1_ * D_IN + (kt) * 64 +    \
                                                        ((sg ^ (r1_ & 7)) << 3)),                \
        (__attribute__((address_space(3))) void*)(&As[(cb)][r1_ * 64 + sg * 8]), 16, 0, 0);      \
  } while (0)
#define STAGE_B(cb, kt, h)                                                                       \
  do {                                                                                           \
    int r0_ = (h) * 128 + sr;                                                                    \
    int r1_ = r0_ + 64;                                                                          \
    __builtin_amdgcn_global_load_lds(                                                            \
        (const __attribute__((address_space(1))) void*)(Bb + (size_t)r0_ * D_IN + (kt) * 64 +    \
                                                        ((sg ^ (r0_ & 7)) << 3)),                \
        (__attribute__((address_space(3))) void*)(&Bs[(cb)][r0_ * 64 + sg * 8]), 16, 0, 0);      \
    __builtin_amdgcn_global_load_lds(                                                            \
        (const __attribute__((address_space(1))) void*)(Bb + (size_t)r1_ * D_IN + (kt) * 64 +    \
                                                        ((sg ^ (r1_ & 7)) << 3)),                \
        (__attribute__((address_space(3))) void*)(&Bs[(cb)][r1_ * 64 + sg * 8]), 16, 0, 0);      \
  } while (0)

  // prologue: K-tile 0 fully + B of K-tile 1 (12 loads; newest 4 = B(1))
  STAGE_A(0, 0, 0); STAGE_A(0, 0, 1);
  STAGE_B(0, 0, 0); STAGE_B(0, 0, 1);
  STAGE_B(1, 1, 0); STAGE_B(1, 1, 1);
  asm volatile("s_waitcnt vmcnt(4)" ::: "memory");
  __builtin_amdgcn_s_barrier();

#pragma unroll 2
  for (int kt = 0; kt < NKT; ++kt) {
    int c = kt & 1;
    const unsigned short* Ap = &As[c][0];
    const unsigned short* Bp = &Bs[c][0];
    bf16x8 b0[4], b1[4];
#pragma unroll
    for (int q = 0; q < 4; ++q) {
      if (q == 0) {
#pragma unroll
        for (int fn = 0; fn < 4; ++fn) {
          b0[fn] = *(const bf16x8*)(Bp + brow0 + fn * 1024 + swz0);
          b1[fn] = *(const bf16x8*)(Bp + brow0 + fn * 1024 + swz1);
        }
      }
      bf16x8 a00 = *(const bf16x8*)(Ap + arow0 + (2 * q) * 1024 + swz0);
      bf16x8 a01 = *(const bf16x8*)(Ap + arow0 + (2 * q) * 1024 + swz1);
      bf16x8 a10 = *(const bf16x8*)(Ap + arow0 + (2 * q + 1) * 1024 + swz0);
      bf16x8 a11 = *(const bf16x8*)(Ap + arow0 + (2 * q + 1) * 1024 + swz1);
      if (q == 0)      { if (kt + 1 < NKT) STAGE_A(c ^ 1, kt + 1, 0); }
      else if (q == 1) { if (kt + 1 < NKT) STAGE_A(c ^ 1, kt + 1, 1); }
      else if (q == 2) { if (kt + 2 < NKT) STAGE_B(c, kt + 2, 0); }
      else             { if (kt + 2 < NKT) STAGE_B(c, kt + 2, 1); }
      __builtin_amdgcn_s_barrier();
      asm volatile("s_waitcnt lgkmcnt(0)" ::: "memory");
      __builtin_amdgcn_s_setprio(1);
#pragma unroll
      for (int fn = 0; fn < 4; ++fn) {
        acc[2 * q][fn]     = __builtin_amdgcn_mfma_f32_16x16x32_bf16(a00, b0[fn], acc[2 * q][fn], 0, 0, 0);
        acc[2 * q][fn]     = __builtin_amdgcn_mfma_f32_16x16x32_bf16(a01, b1[fn], acc[2 * q][fn], 0, 0, 0);
        acc[2 * q + 1][fn] = __builtin_amdgcn_mfma_f32_16x16x32_bf16(a10, b0[fn], acc[2 * q + 1][fn], 0, 0, 0);
        acc[2 * q + 1][fn] = __builtin_amdgcn_mfma_f32_16x16x32_bf16(a11, b1[fn], acc[2 * q + 1][fn], 0, 0, 0);
      }
      __builtin_amdgcn_s_setprio(0);
      if (q == 3) {
        if (kt < NKT - 2)        asm volatile("s_waitcnt vmcnt(4)" ::: "memory");
        else if (kt == NKT - 2)  asm volatile("s_waitcnt vmcnt(0)" ::: "memory");
      }
      __builtin_amdgcn_s_barrier();
    }
  }
#undef STAGE_A
#undef STAGE_B

  // epilogue: bias + relu + bf16 store
  float bev[4];
#pragma unroll
  for (int fn = 0; fn < 4; ++fn)
    bev[fn] = be[e * H_DIM + wn * 64 + fn * 16 + lr];
#pragma unroll
  for (int fm = 0; fm < 8; ++fm) {
#pragma unroll
    for (int fn = 0; fn < 4; ++fn) {
      int col = wn * 64 + fn * 16 + lr;
#pragma unroll
      for (int j = 0; j < 4; ++j) {
        int row = m0 + wm * 128 + fm * 16 + lq * 4 + j;
        float vv = fmaxf(acc[fm][fn][j] + bev[fn], 0.f);
        E[(size_t)row * (N_EXP * H_DIM) + e * H_DIM + col] = f2bf(vv);
      }
    }
  }
}

// ---------------------------------------------------------------------------
// Kernel 4: combine. towers[t][b][h] = sum_e G[b][t][e] * E[b][e][h]
// ---------------------------------------------------------------------------
__global__ void k_combine(const unsigned short* __restrict__ E, const float* __restrict__ G,
                          float* __restrict__ out) {
  int t = threadIdx.x;
  int wv = t >> 6, l = t & 63;
  int r = blockIdx.x * 4 + wv;
  const unsigned short* er = E + (size_t)r * (N_EXP * H_DIM);
  const float* g = G + (size_t)r * 32;
  float acc[4][4];
#pragma unroll
  for (int i = 0; i < 4; ++i)
#pragma unroll
    for (int j = 0; j < 4; ++j) acc[i][j] = 0.f;
#pragma unroll
  for (int e = 0; e < 8; ++e) {
    ushort4 u = *(const ushort4*)(er + e * H_DIM + l * 4);
    float f0 = bf2f(u.x), f1 = bf2f(u.y), f2 = bf2f(u.z), f3 = bf2f(u.w);
#pragma unroll
    for (int tk = 0; tk < 4; ++tk) {
      float gv = g[tk * 8 + e];
      acc[tk][0] += gv * f0;
      acc[tk][1] += gv * f1;
      acc[tk][2] += gv * f2;
      acc[tk][3] += gv * f3;
    }
  }
#pragma unroll
  for (int tk = 0; tk < 4; ++tk) {
    float4 o = make_float4(acc[tk][0], acc[tk][1], acc[tk][2], acc[tk][3]);
    *(float4*)(out + ((size_t)tk * B_ROWS + r) * H_DIM + l * 4) = o;
  }
}

extern "C" void kernel_launch(void* const* d_in, const int* in_sizes, int n_in,
                              void* d_out, int out_size, void* d_ws, size_t ws_size,
                              hipStream_t stream) {
  const float* x  = (const float*)d_in[0];
  const float* We = (const float*)d_in[1];
  const float* be = (const float*)d_in[2];
  const float* Wg = (const float*)d_in[3];
  const float* bg = (const float*)d_in[4];
  float* out = (float*)d_out;
  char* ws = (char*)d_ws;
  unsigned short* x_b  = (unsigned short*)(ws + WS_XB);
  unsigned short* We_t = (unsigned short*)(ws + WS_WET);
  unsigned short* Wg_t = (unsigned short*)(ws + WS_WGT);
  float*          G    = (float*)(ws + WS_G);
  unsigned short* E    = (unsigned short*)(ws + WS_E);

  hipMemsetAsync(G, 0, (size_t)B_ROWS * 32 * sizeof(float), stream);
  k_prep_w<<<513, 256, 0, stream>>>(We, Wg, We_t, Wg_t);
  k_gates<<<dim3(B_ROWS / 64, 4), 256, 0, stream>>>(x, Wg_t, x_b, G);
  k_expert<<<512 + 32, 512, 0, stream>>>(x_b, We_t, be, bg, G, E);
  k_combine<<<B_ROWS / 4, 256, 0, stream>>>(E, G, out);
}

// Round 2
// 227.801 us; speedup vs baseline: 1.1073x; 1.1073x over previous
//
#include <hip/hip_runtime.h>

#define B_ROWS 16384
#define D_IN   1024
#define H_DIM  256
#define N_EXP  8
#define N_TASK 4
#define NKT    16   // K-tiles of 64 in D_IN

typedef short bf16x8 __attribute__((ext_vector_type(8)));
typedef float f32x4  __attribute__((ext_vector_type(4)));
typedef unsigned short u16x8 __attribute__((ext_vector_type(8)));

static __device__ __forceinline__ unsigned short f2bf(float f) {
  unsigned int u = __float_as_uint(f);
  u += 0x7fffu + ((u >> 16) & 1u);   // RNE
  return (unsigned short)(u >> 16);
}
static __device__ __forceinline__ float bf2f(unsigned short u) {
  return __uint_as_float(((unsigned int)u) << 16);
}

// workspace layout (bytes)
#define WS_XB   0u          // ushort[16384*1024]  = 33,554,432 B
#define WS_WET  33554432u   // ushort[8*256*1024]  =  4,194,304 B
#define WS_WGT  37748736u   // ushort[32*1024]     =     65,536 B
#define WS_G    37814272u   // float [16384*32]    =  2,097,152 B (final probs)
#define WS_E    39911424u   // ushort[16384*2048]  = 67,108,864 B

// ---------------------------------------------------------------------------
// Kernel 1: cast+transpose We -> We_t[e][h][k] bf16 ; Wg -> Wg_t[n][k] bf16
// blocks [0,512): We tiles. blocks [512,544): one (task,expert) Wg row each.
// ---------------------------------------------------------------------------
__global__ void k_prep_w(const float* __restrict__ We, const float* __restrict__ Wg,
                         unsigned short* __restrict__ We_t, unsigned short* __restrict__ Wg_t) {
  int bid = blockIdx.x;
  int t = threadIdx.x;
  if (bid < 512) {
    // one 64x64 tile of We[e]: [k][h] -> [h][k]
    int e = bid >> 6;
    int tl = bid & 63;
    int k0 = (tl >> 2) * 64, h0 = (tl & 3) * 64;
    __shared__ unsigned short tile[64][72];   // [h][k], padded
    const float* src = We + (size_t)e * (D_IN * H_DIM);
#pragma unroll
    for (int i = 0; i < 4; ++i) {
      int kk = (t >> 4) + i * 16;
      int hh = (t & 15) * 4;
      float4 v = *(const float4*)(src + (size_t)(k0 + kk) * H_DIM + h0 + hh);
      tile[hh + 0][kk] = f2bf(v.x);
      tile[hh + 1][kk] = f2bf(v.y);
      tile[hh + 2][kk] = f2bf(v.z);
      tile[hh + 3][kk] = f2bf(v.w);
    }
    __syncthreads();
    unsigned short* dst = We_t + (size_t)e * (H_DIM * D_IN);
#pragma unroll
    for (int i = 0; i < 4; ++i) {
      int hh = (t >> 4) + i * 16;
      int kk = (t & 15) * 4;
      ushort4 u = *(const ushort4*)&tile[hh][kk];
      *(ushort4*)(dst + (size_t)(h0 + hh) * D_IN + k0 + kk) = u;
    }
  } else {
    // Wg[4][1024][8] -> Wg_t[n][k], one n per block, 4 k per thread
    int n = bid - 512;               // 0..31
    int tsk = n >> 3, e = n & 7;
    int k = t * 4;
    const float* src = Wg + (size_t)tsk * (D_IN * 8) + e;
    ushort4 u;
    u.x = f2bf(src[(size_t)(k + 0) * 8]);
    u.y = f2bf(src[(size_t)(k + 1) * 8]);
    u.z = f2bf(src[(size_t)(k + 2) * 8]);
    u.w = f2bf(src[(size_t)(k + 3) * 8]);
    *(ushort4*)(Wg_t + (size_t)n * D_IN + k) = u;
  }
}

// ---------------------------------------------------------------------------
// Kernel 2: fused cast + gate logits (full K, no atomics) + in-register
// softmax -> final probs G. 256 blocks x 64 rows. Softmax over experts =
// reduction across lanes differing in bits 0..2 (3x shfl_xor).
// ---------------------------------------------------------------------------
__global__ void k_gates(const float* __restrict__ x,
                        const unsigned short* __restrict__ Wg_t,
                        unsigned short* __restrict__ x_b,
                        const float* __restrict__ bg,
                        float* __restrict__ G) {
  __shared__ unsigned short xs[64][136];
  __shared__ unsigned short wgs[32][136];
  int m0 = blockIdx.x * 64;
  int t = threadIdx.x;
  int wv = t >> 6, l = t & 63;
  f32x4 acc0 = {0.f, 0.f, 0.f, 0.f}, acc1 = {0.f, 0.f, 0.f, 0.f};

  for (int k0 = 0; k0 < D_IN; k0 += 128) {
    {
      int r = t >> 2;
      int cb = (t & 3) * 32;
      const float* p = x + (size_t)(m0 + r) * D_IN + k0 + cb;
      unsigned short* q = x_b + (size_t)(m0 + r) * D_IN + k0 + cb;
#pragma unroll
      for (int i = 0; i < 8; ++i) {
        float4 v = *(const float4*)(p + i * 4);
        ushort4 u;
        u.x = f2bf(v.x); u.y = f2bf(v.y); u.z = f2bf(v.z); u.w = f2bf(v.w);
        *(ushort4*)&xs[r][cb + i * 4] = u;
        *(ushort4*)(q + i * 4) = u;
      }
    }
    {
      int n = t >> 3;
      int kk = (t & 7) * 16;
      const unsigned short* p = Wg_t + (size_t)n * D_IN + k0 + kk;
#pragma unroll
      for (int i = 0; i < 4; ++i)
        *(ushort4*)&wgs[n][kk + i * 4] = *(const ushort4*)(p + i * 4);
    }
    __syncthreads();
#pragma unroll
    for (int kk = 0; kk < 4; ++kk) {
      bf16x8 a  = *(const bf16x8*)&xs[wv * 16 + (l & 15)][kk * 32 + (l >> 4) * 8];
      bf16x8 b0 = *(const bf16x8*)&wgs[(l & 15)][kk * 32 + (l >> 4) * 8];
      bf16x8 b1 = *(const bf16x8*)&wgs[16 + (l & 15)][kk * 32 + (l >> 4) * 8];
      acc0 = __builtin_amdgcn_mfma_f32_16x16x32_bf16(a, b0, acc0, 0, 0, 0);
      acc1 = __builtin_amdgcn_mfma_f32_16x16x32_bf16(a, b1, acc1, 0, 0, 0);
    }
    __syncthreads();
  }

  // acc0[j]: row = m0+wv*16+(l>>4)*4+j, col = l&15 (tasks 0,1)
  // acc1[j]: same row, col = 16+(l&15)   (tasks 2,3)
  // softmax over e (col&7): lanes of one group differing in bits 0..2
  int colb = l & 15;
  int rbase = m0 + wv * 16 + (l >> 4) * 4;
  float bga = bg[colb], bgb = bg[16 + colb];
#pragma unroll
  for (int j = 0; j < 4; ++j) {
    float va = acc0[j] + bga;
    float vb = acc1[j] + bgb;
    float mxa = va, mxb = vb;
#pragma unroll
    for (int d = 1; d < 8; d <<= 1) {
      mxa = fmaxf(mxa, __shfl_xor(mxa, d));
      mxb = fmaxf(mxb, __shfl_xor(mxb, d));
    }
    va = __expf(va - mxa); vb = __expf(vb - mxb);
    float sa = va, sb = vb;
#pragma unroll
    for (int d = 1; d < 8; d <<= 1) {
      sa += __shfl_xor(sa, d);
      sb += __shfl_xor(sb, d);
    }
    va /= sa; vb /= sb;
    G[(size_t)(rbase + j) * 32 + colb]      = va;
    G[(size_t)(rbase + j) * 32 + 16 + colb] = vb;
  }
}

// ---------------------------------------------------------------------------
// Kernel 3: expert GEMM — 256x256 tile, 8 waves (2Mx4N), BK=64, 4-phase
// pipelined K-loop with counted vmcnt (T3+T4), XOR-swizzled LDS (T2),
// setprio around MFMA (T5), XCD block swizzle (T1). Grid = 512 exactly.
// ---------------------------------------------------------------------------
__global__ __launch_bounds__(512, 2) void k_expert(const unsigned short* __restrict__ x_b,
                                                   const unsigned short* __restrict__ We_t,
                                                   const float* __restrict__ be,
                                                   unsigned short* __restrict__ E) {
  __shared__ unsigned short As[2][256 * 64];   // 64 KiB
  __shared__ unsigned short Bs[2][256 * 64];   // 64 KiB
  int bid = blockIdx.x;
  int t = threadIdx.x;

  // XCD swizzle: 8 consecutive same-XCD slots share one m-tile's A panel
  int xcd = bid & 7;
  int idx = bid >> 3;              // 0..63
  int m   = xcd * 8 + (idx >> 3);  // m-tile 0..63
  int e   = idx & 7;
  int m0  = m * 256;

  int w  = t >> 6, l = t & 63;
  int wm = w >> 2, wn = w & 3;     // wave tile: rows wm*128..+128, cols wn*64..+64
  int lr = l & 15, lq = l >> 4;

  const unsigned short* Ab = x_b + (size_t)m0 * D_IN;
  const unsigned short* Bb = We_t + (size_t)e * (H_DIM * D_IN);

  const int sr = t >> 3, sg = t & 7;                 // staging row / 16B granule
  const int swz0 = ((lq ^ (lr & 7)) << 3);           // ks=0 swizzled granule (ushorts)
  const int swz1 = (((4 + lq) ^ (lr & 7)) << 3);     // ks=1
  const int arow0 = (wm * 128 + lr) << 6;            // + fm*1024
  const int brow0 = (wn * 64 + lr) << 6;             // + fn*1024

  f32x4 acc[8][4];
#pragma unroll
  for (int i = 0; i < 8; ++i)
#pragma unroll
    for (int j = 0; j < 4; ++j) acc[i][j] = (f32x4){0.f, 0.f, 0.f, 0.f};

  // half-tile = 128 rows x 64 k bf16 = 16 KiB = 2 load instrs (512 thr x 16 B)
  // dest is linear (base + t*16); source k-granule pre-swizzled (rule 21)
#define STAGE_A(cb, kt, h)                                                                       \
  do {                                                                                           \
    int r0_ = (h) * 128 + sr;                                                                    \
    int r1_ = r0_ + 64;                                                                          \
    __builtin_amdgcn_global_load_lds(                                                            \
        (const __attribute__((address_space(1))) void*)(Ab + (size_t)r0_ * D_IN + (kt) * 64 +    \
                                                        ((sg ^ (r0_ & 7)) << 3)),                \
        (__attribute__((address_space(3))) void*)(&As[(cb)][r0_ * 64 + sg * 8]), 16, 0, 0);      \
    __builtin_amdgcn_global_load_lds(                                                            \
        (const __attribute__((address_space(1))) void*)(Ab + (size_t)r1_ * D_IN + (kt) * 64 +    \
                                                        ((sg ^ (r1_ & 7)) << 3)),                \
        (__attribute__((address_space(3))) void*)(&As[(cb)][r1_ * 64 + sg * 8]), 16, 0, 0);      \
  } while (0)
#define STAGE_B(cb, kt, h)                                                                       \
  do {                                                                                           \
    int r0_ = (h) * 128 + sr;                                                                    \
    int r1_ = r0_ + 64;                                                                          \
    __builtin_amdgcn_global_load_lds(                                                            \
        (const __attribute__((address_space(1))) void*)(Bb + (size_t)r0_ * D_IN + (kt) * 64 +    \
                                                        ((sg ^ (r0_ & 7)) << 3)),                \
        (__attribute__((address_space(3))) void*)(&Bs[(cb)][r0_ * 64 + sg * 8]), 16, 0, 0);      \
    __builtin_amdgcn_global_load_lds(                                                            \
        (const __attribute__((address_space(1))) void*)(Bb + (size_t)r1_ * D_IN + (kt) * 64 +    \
                                                        ((sg ^ (r1_ & 7)) << 3)),                \
        (__attribute__((address_space(3))) void*)(&Bs[(cb)][r1_ * 64 + sg * 8]), 16, 0, 0);      \
  } while (0)

  // prologue: K-tile 0 fully + B of K-tile 1 (12 loads; newest 4 = B(1))
  STAGE_A(0, 0, 0); STAGE_A(0, 0, 1);
  STAGE_B(0, 0, 0); STAGE_B(0, 0, 1);
  STAGE_B(1, 1, 0); STAGE_B(1, 1, 1);
  asm volatile("s_waitcnt vmcnt(4)" ::: "memory");
  __builtin_amdgcn_s_barrier();

#pragma unroll 2
  for (int kt = 0; kt < NKT; ++kt) {
    int c = kt & 1;
    const unsigned short* Ap = &As[c][0];
    const unsigned short* Bp = &Bs[c][0];
    bf16x8 b0[4], b1[4];
#pragma unroll
    for (int q = 0; q < 4; ++q) {
      if (q == 0) {
#pragma unroll
        for (int fn = 0; fn < 4; ++fn) {
          b0[fn] = *(const bf16x8*)(Bp + brow0 + fn * 1024 + swz0);
          b1[fn] = *(const bf16x8*)(Bp + brow0 + fn * 1024 + swz1);
        }
      }
      bf16x8 a00 = *(const bf16x8*)(Ap + arow0 + (2 * q) * 1024 + swz0);
      bf16x8 a01 = *(const bf16x8*)(Ap + arow0 + (2 * q) * 1024 + swz1);
      bf16x8 a10 = *(const bf16x8*)(Ap + arow0 + (2 * q + 1) * 1024 + swz0);
      bf16x8 a11 = *(const bf16x8*)(Ap + arow0 + (2 * q + 1) * 1024 + swz1);
      if (q == 0)      { if (kt + 1 < NKT) STAGE_A(c ^ 1, kt + 1, 0); }
      else if (q == 1) { if (kt + 1 < NKT) STAGE_A(c ^ 1, kt + 1, 1); }
      else if (q == 2) { if (kt + 2 < NKT) STAGE_B(c, kt + 2, 0); }
      else             { if (kt + 2 < NKT) STAGE_B(c, kt + 2, 1); }
      __builtin_amdgcn_s_barrier();
      asm volatile("s_waitcnt lgkmcnt(0)" ::: "memory");
      __builtin_amdgcn_s_setprio(1);
#pragma unroll
      for (int fn = 0; fn < 4; ++fn) {
        acc[2 * q][fn]     = __builtin_amdgcn_mfma_f32_16x16x32_bf16(a00, b0[fn], acc[2 * q][fn], 0, 0, 0);
        acc[2 * q][fn]     = __builtin_amdgcn_mfma_f32_16x16x32_bf16(a01, b1[fn], acc[2 * q][fn], 0, 0, 0);
        acc[2 * q + 1][fn] = __builtin_amdgcn_mfma_f32_16x16x32_bf16(a10, b0[fn], acc[2 * q + 1][fn], 0, 0, 0);
        acc[2 * q + 1][fn] = __builtin_amdgcn_mfma_f32_16x16x32_bf16(a11, b1[fn], acc[2 * q + 1][fn], 0, 0, 0);
      }
      __builtin_amdgcn_s_setprio(0);
      if (q == 3) {
        if (kt < NKT - 2)        asm volatile("s_waitcnt vmcnt(4)" ::: "memory");
        else if (kt == NKT - 2)  asm volatile("s_waitcnt vmcnt(0)" ::: "memory");
      }
      __builtin_amdgcn_s_barrier();
    }
  }
#undef STAGE_A
#undef STAGE_B

  // epilogue: bias + relu + bf16 store
  float bev[4];
#pragma unroll
  for (int fn = 0; fn < 4; ++fn)
    bev[fn] = be[e * H_DIM + wn * 64 + fn * 16 + lr];
#pragma unroll
  for (int fm = 0; fm < 8; ++fm) {
#pragma unroll
    for (int fn = 0; fn < 4; ++fn) {
      int col = wn * 64 + fn * 16 + lr;
#pragma unroll
      for (int j = 0; j < 4; ++j) {
        int row = m0 + wm * 128 + fm * 16 + lq * 4 + j;
        float vv = fmaxf(acc[fm][fn][j] + bev[fn], 0.f);
        E[(size_t)row * (N_EXP * H_DIM) + e * H_DIM + col] = f2bf(vv);
      }
    }
  }
}

// ---------------------------------------------------------------------------
// Kernel 4: combine. towers[t][b][h] = sum_e G[b][t][e] * E[b][e][h]
// 2 rows per wave, 16B loads: lane l -> row r+(l>>5), h = (l&31)*8..+8
// ---------------------------------------------------------------------------
__global__ void k_combine(const unsigned short* __restrict__ E, const float* __restrict__ G,
                          float* __restrict__ out) {
  int t = threadIdx.x;
  int wv = t >> 6, l = t & 63;
  int r = blockIdx.x * 8 + wv * 2 + (l >> 5);
  int h0 = (l & 31) * 8;
  const unsigned short* er = E + (size_t)r * (N_EXP * H_DIM) + h0;
  const float* g = G + (size_t)r * 32;
  float garr[32];
#pragma unroll
  for (int c = 0; c < 8; ++c) {
    float4 a = *(const float4*)(g + c * 4);
    garr[c * 4 + 0] = a.x; garr[c * 4 + 1] = a.y;
    garr[c * 4 + 2] = a.z; garr[c * 4 + 3] = a.w;
  }
  float acc[4][8];
#pragma unroll
  for (int tk = 0; tk < 4; ++tk)
#pragma unroll
    for (int i = 0; i < 8; ++i) acc[tk][i] = 0.f;
#pragma unroll
  for (int e = 0; e < 8; ++e) {
    u16x8 u = *(const u16x8*)(er + e * H_DIM);
#pragma unroll
    for (int i = 0; i < 8; ++i) {
      float f = bf2f((unsigned short)u[i]);
#pragma unroll
      for (int tk = 0; tk < 4; ++tk)
        acc[tk][i] += garr[tk * 8 + e] * f;
    }
  }
#pragma unroll
  for (int tk = 0; tk < 4; ++tk) {
    float* o = out + ((size_t)tk * B_ROWS + r) * H_DIM + h0;
    *(float4*)(o)     = make_float4(acc[tk][0], acc[tk][1], acc[tk][2], acc[tk][3]);
    *(float4*)(o + 4) = make_float4(acc[tk][4], acc[tk][5], acc[tk][6], acc[tk][7]);
  }
}

extern "C" void kernel_launch(void* const* d_in, const int* in_sizes, int n_in,
                              void* d_out, int out_size, void* d_ws, size_t ws_size,
                              hipStream_t stream) {
  const float* x  = (const float*)d_in[0];
  const float* We = (const float*)d_in[1];
  const float* be = (const float*)d_in[2];
  const float* Wg = (const float*)d_in[3];
  const float* bg = (const float*)d_in[4];
  float* out = (float*)d_out;
  char* ws = (char*)d_ws;
  unsigned short* x_b  = (unsigned short*)(ws + WS_XB);
  unsigned short* We_t = (unsigned short*)(ws + WS_WET);
  unsigned short* Wg_t = (unsigned short*)(ws + WS_WGT);
  float*          G    = (float*)(ws + WS_G);
  unsigned short* E    = (unsigned short*)(ws + WS_E);

  k_prep_w<<<544, 256, 0, stream>>>(We, Wg, We_t, Wg_t);
  k_gates<<<B_ROWS / 64, 256, 0, stream>>>(x, Wg_t, x_b, bg, G);
  k_expert<<<512, 512, 0, stream>>>(x_b, We_t, be, E);
  k_combine<<<B_ROWS / 8, 256, 0, stream>>>(E, G, out);
}

// Round 3
// 208.118 us; speedup vs baseline: 1.2120x; 1.0946x over previous
//
#include <hip/hip_runtime.h>

#define B_ROWS 16384
#define D_IN   1024
#define H_DIM  256
#define N_EXP  8
#define N_TASK 4
#define NKT    16   // K-tiles of 64 in D_IN

typedef short bf16x8 __attribute__((ext_vector_type(8)));
typedef float f32x4  __attribute__((ext_vector_type(4)));
typedef unsigned short u16x8 __attribute__((ext_vector_type(8)));

static __device__ __forceinline__ unsigned short f2bf(float f) {
  unsigned int u = __float_as_uint(f);
  u += 0x7fffu + ((u >> 16) & 1u);   // RNE
  return (unsigned short)(u >> 16);
}

// workspace layout (bytes)
#define WS_XB   0u          // ushort[16384*1024]  = 33,554,432 B
#define WS_WET  33554432u   // ushort[8*256*1024]  =  4,194,304 B
#define WS_WGT  37748736u   // ushort[32*1024]     =     65,536 B
#define WS_GT   37814272u   // float [32*16384]    =  2,097,152 B (transposed probs Gt[t*8+e][row])

// ---------------------------------------------------------------------------
// Kernel 1: prep. blocks [0,512): We cast+transpose -> We_t[e][h][k].
// blocks [512,544): Wg -> Wg_t[n][k]. blocks [544,8736): x fp32 -> x_b bf16.
// ---------------------------------------------------------------------------
__global__ void k_prep_w(const float* __restrict__ x, const float* __restrict__ We,
                         const float* __restrict__ Wg,
                         unsigned short* __restrict__ x_b,
                         unsigned short* __restrict__ We_t, unsigned short* __restrict__ Wg_t) {
  int bid = blockIdx.x;
  int t = threadIdx.x;
  if (bid < 512) {
    // one 64x64 tile of We[e]: [k][h] -> [h][k]
    int e = bid >> 6;
    int tl = bid & 63;
    int k0 = (tl >> 2) * 64, h0 = (tl & 3) * 64;
    __shared__ unsigned short tile[64][72];   // [h][k], padded
    const float* src = We + (size_t)e * (D_IN * H_DIM);
#pragma unroll
    for (int i = 0; i < 4; ++i) {
      int kk = (t >> 4) + i * 16;
      int hh = (t & 15) * 4;
      float4 v = *(const float4*)(src + (size_t)(k0 + kk) * H_DIM + h0 + hh);
      tile[hh + 0][kk] = f2bf(v.x);
      tile[hh + 1][kk] = f2bf(v.y);
      tile[hh + 2][kk] = f2bf(v.z);
      tile[hh + 3][kk] = f2bf(v.w);
    }
    __syncthreads();
    unsigned short* dst = We_t + (size_t)e * (H_DIM * D_IN);
#pragma unroll
    for (int i = 0; i < 4; ++i) {
      int hh = (t >> 4) + i * 16;
      int kk = (t & 15) * 4;
      ushort4 u = *(const ushort4*)&tile[hh][kk];
      *(ushort4*)(dst + (size_t)(h0 + hh) * D_IN + k0 + kk) = u;
    }
  } else if (bid < 544) {
    // Wg[4][1024][8] -> Wg_t[n][k], one n per block, 4 k per thread
    int n = bid - 512;               // 0..31
    int tsk = n >> 3, e = n & 7;
    int k = t * 4;
    const float* src = Wg + (size_t)tsk * (D_IN * 8) + e;
    ushort4 u;
    u.x = f2bf(src[(size_t)(k + 0) * 8]);
    u.y = f2bf(src[(size_t)(k + 1) * 8]);
    u.z = f2bf(src[(size_t)(k + 2) * 8]);
    u.w = f2bf(src[(size_t)(k + 3) * 8]);
    *(ushort4*)(Wg_t + (size_t)n * D_IN + k) = u;
  } else {
    // x cast: 8192 blocks x 256 thr x 8 elems
    size_t base = (size_t)(bid - 544) * 2048 + (size_t)t * 8;
    float4 v0 = *(const float4*)(x + base);
    float4 v1 = *(const float4*)(x + base + 4);
    u16x8 u;
    u[0] = (short)f2bf(v0.x); u[1] = (short)f2bf(v0.y);
    u[2] = (short)f2bf(v0.z); u[3] = (short)f2bf(v0.w);
    u[4] = (short)f2bf(v1.x); u[5] = (short)f2bf(v1.y);
    u[6] = (short)f2bf(v1.z); u[7] = (short)f2bf(v1.w);
    *(u16x8*)(x_b + base) = u;
  }
}

// ---------------------------------------------------------------------------
// Kernel 2: gate logits (bf16 MFMA, full K) + in-register softmax ->
// TRANSPOSED probs Gt[t*8+e][row]. 256 blocks x 64 rows.
// ---------------------------------------------------------------------------
__global__ void k_gates(const unsigned short* __restrict__ x_b,
                        const unsigned short* __restrict__ Wg_t,
                        const float* __restrict__ bg,
                        float* __restrict__ Gt) {
  __shared__ unsigned short xs[64][136];
  __shared__ unsigned short wgs[32][136];
  int m0 = blockIdx.x * 64;
  int t = threadIdx.x;
  int wv = t >> 6, l = t & 63;
  f32x4 acc0 = {0.f, 0.f, 0.f, 0.f}, acc1 = {0.f, 0.f, 0.f, 0.f};

  for (int k0 = 0; k0 < D_IN; k0 += 128) {
    {
      int r = t >> 2;
      int cb = (t & 3) * 32;
      const unsigned short* p = x_b + (size_t)(m0 + r) * D_IN + k0 + cb;
#pragma unroll
      for (int i = 0; i < 4; ++i)
        *(u16x8*)&xs[r][cb + i * 8] = *(const u16x8*)(p + i * 8);
    }
    {
      int n = t >> 3;
      int kk = (t & 7) * 16;
      const unsigned short* p = Wg_t + (size_t)n * D_IN + k0 + kk;
#pragma unroll
      for (int i = 0; i < 4; ++i)
        *(ushort4*)&wgs[n][kk + i * 4] = *(const ushort4*)(p + i * 4);
    }
    __syncthreads();
#pragma unroll
    for (int kk = 0; kk < 4; ++kk) {
      bf16x8 a  = *(const bf16x8*)&xs[wv * 16 + (l & 15)][kk * 32 + (l >> 4) * 8];
      bf16x8 b0 = *(const bf16x8*)&wgs[(l & 15)][kk * 32 + (l >> 4) * 8];
      bf16x8 b1 = *(const bf16x8*)&wgs[16 + (l & 15)][kk * 32 + (l >> 4) * 8];
      acc0 = __builtin_amdgcn_mfma_f32_16x16x32_bf16(a, b0, acc0, 0, 0, 0);
      acc1 = __builtin_amdgcn_mfma_f32_16x16x32_bf16(a, b1, acc1, 0, 0, 0);
    }
    __syncthreads();
  }

  // acc0[j]: row = m0+wv*16+(l>>4)*4+j, gate-col = l&15 (tasks 0,1)
  // acc1[j]: same row, gate-col = 16+(l&15)  (tasks 2,3)
  int colb = l & 15;
  int rbase = m0 + wv * 16 + (l >> 4) * 4;
  float bga = bg[colb], bgb = bg[16 + colb];
#pragma unroll
  for (int j = 0; j < 4; ++j) {
    float va = acc0[j] + bga;
    float vb = acc1[j] + bgb;
    float mxa = va, mxb = vb;
#pragma unroll
    for (int d = 1; d < 8; d <<= 1) {
      mxa = fmaxf(mxa, __shfl_xor(mxa, d));
      mxb = fmaxf(mxb, __shfl_xor(mxb, d));
    }
    va = __expf(va - mxa); vb = __expf(vb - mxb);
    float sa = va, sb = vb;
#pragma unroll
    for (int d = 1; d < 8; d <<= 1) {
      sa += __shfl_xor(sa, d);
      sb += __shfl_xor(sb, d);
    }
    va /= sa; vb /= sb;
    Gt[(size_t)colb * B_ROWS + rbase + j]        = va;
    Gt[(size_t)(16 + colb) * B_ROWS + rbase + j] = vb;
  }
}

// ---------------------------------------------------------------------------
// Kernel 3: expert GEMM + FUSED gated combine. 256x256 tile, 8 waves,
// BK=64, 4-phase pipelined K-loop (T3+T4), XOR-swizzle (T2), setprio (T5),
// XCD swizzle (T1). B-columns interleave experts: n -> (e=(n>>3)&7,
// h = hs*32 + (n>>6)*8 + (n&7)), so each lane's 4 fn-frags hold experts
// {0,2,4,6}+hi (hi=lr>>3); expert-sum = 4 FMA + shfl_xor(8). Writes towers
// directly — E never hits HBM.
// ---------------------------------------------------------------------------
__global__ __launch_bounds__(512, 2) void k_expert(const unsigned short* __restrict__ x_b,
                                                   const unsigned short* __restrict__ We_t,
                                                   const float* __restrict__ be,
                                                   const float* __restrict__ Gt,
                                                   float* __restrict__ out) {
  __shared__ unsigned short As[2][256 * 64];   // 64 KiB
  __shared__ unsigned short Bs[2][256 * 64];   // 64 KiB
  int bid = blockIdx.x;
  int t = threadIdx.x;

  // XCD swizzle: 8 consecutive same-XCD slots share one m-tile's A panel
  int xcd = bid & 7;
  int idx = bid >> 3;              // 0..63
  int m   = xcd * 8 + (idx >> 3);  // m-tile 0..63
  int hs  = idx & 7;               // h-slice 0..7 (32 cols per expert)
  int m0  = m * 256;

  int w  = t >> 6, l = t & 63;
  int wm = w >> 2, wn = w & 3;     // wave tile: rows wm*128..+128, cols wn*64..+64
  int lr = l & 15, lq = l >> 4;

  const unsigned short* Ab = x_b + (size_t)m0 * D_IN;

  const int sr = t >> 3, sg = t & 7;                 // staging row / 16B granule
  const int swz0 = ((lq ^ (lr & 7)) << 3);           // ks=0 swizzled granule (ushorts)
  const int swz1 = (((4 + lq) ^ (lr & 7)) << 3);     // ks=1
  const int arow0 = (wm * 128 + lr) << 6;            // + fm*1024
  const int brow0 = (wn * 64 + lr) << 6;             // + fn*1024

  // B global source rows for the 4 LDS rows this thread stages
  // (expert-interleaved mapping), swizzle pre-applied to source granule.
  size_t bsrc[4];
#pragma unroll
  for (int q2 = 0; q2 < 4; ++q2) {
    int rq = q2 * 64 + sr;                       // LDS row 0..255
    int me = (rq >> 3) & 7;
    int mh = hs * 32 + ((rq >> 6) & 3) * 8 + (rq & 7);
    bsrc[q2] = (size_t)(me * H_DIM + mh) * D_IN + (size_t)((sg ^ (rq & 7)) << 3);
  }

  f32x4 acc[8][4];
#pragma unroll
  for (int i = 0; i < 8; ++i)
#pragma unroll
    for (int j = 0; j < 4; ++j) acc[i][j] = (f32x4){0.f, 0.f, 0.f, 0.f};

#define STAGE_A(cb, kt, h)                                                                       \
  do {                                                                                           \
    int r0_ = (h) * 128 + sr;                                                                    \
    int r1_ = r0_ + 64;                                                                          \
    __builtin_amdgcn_global_load_lds(                                                            \
        (const __attribute__((address_space(1))) void*)(Ab + (size_t)r0_ * D_IN + (kt) * 64 +    \
                                                        ((sg ^ (r0_ & 7)) << 3)),                \
        (__attribute__((address_space(3))) void*)(&As[(cb)][r0_ * 64 + sg * 8]), 16, 0, 0);      \
    __builtin_amdgcn_global_load_lds(                                                            \
        (const __attribute__((address_space(1))) void*)(Ab + (size_t)r1_ * D_IN + (kt) * 64 +    \
                                                        ((sg ^ (r1_ & 7)) << 3)),                \
        (__attribute__((address_space(3))) void*)(&As[(cb)][r1_ * 64 + sg * 8]), 16, 0, 0);      \
  } while (0)
#define STAGE_B(cb, kt, h)                                                                       \
  do {                                                                                           \
    int r0_ = (h) * 128 + sr;                                                                    \
    int r1_ = r0_ + 64;                                                                          \
    __builtin_amdgcn_global_load_lds(                                                            \
        (const __attribute__((address_space(1))) void*)(We_t + bsrc[2 * (h)] + (kt) * 64),       \
        (__attribute__((address_space(3))) void*)(&Bs[(cb)][r0_ * 64 + sg * 8]), 16, 0, 0);      \
    __builtin_amdgcn_global_load_lds(                                                            \
        (const __attribute__((address_space(1))) void*)(We_t + bsrc[2 * (h) + 1] + (kt) * 64),   \
        (__attribute__((address_space(3))) void*)(&Bs[(cb)][r1_ * 64 + sg * 8]), 16, 0, 0);      \
  } while (0)

  // prologue: K-tile 0 fully + B of K-tile 1 (12 loads; newest 4 = B(1))
  STAGE_A(0, 0, 0); STAGE_A(0, 0, 1);
  STAGE_B(0, 0, 0); STAGE_B(0, 0, 1);
  STAGE_B(1, 1, 0); STAGE_B(1, 1, 1);
  asm volatile("s_waitcnt vmcnt(4)" ::: "memory");
  __builtin_amdgcn_s_barrier();

#pragma unroll 2
  for (int kt = 0; kt < NKT; ++kt) {
    int c = kt & 1;
    const unsigned short* Ap = &As[c][0];
    const unsigned short* Bp = &Bs[c][0];
    bf16x8 b0[4], b1[4];
#pragma unroll
    for (int q = 0; q < 4; ++q) {
      if (q == 0) {
#pragma unroll
        for (int fn = 0; fn < 4; ++fn) {
          b0[fn] = *(const bf16x8*)(Bp + brow0 + fn * 1024 + swz0);
          b1[fn] = *(const bf16x8*)(Bp + brow0 + fn * 1024 + swz1);
        }
      }
      bf16x8 a00 = *(const bf16x8*)(Ap + arow0 + (2 * q) * 1024 + swz0);
      bf16x8 a01 = *(const bf16x8*)(Ap + arow0 + (2 * q) * 1024 + swz1);
      bf16x8 a10 = *(const bf16x8*)(Ap + arow0 + (2 * q + 1) * 1024 + swz0);
      bf16x8 a11 = *(const bf16x8*)(Ap + arow0 + (2 * q + 1) * 1024 + swz1);
      if (q == 0)      { if (kt + 1 < NKT) STAGE_A(c ^ 1, kt + 1, 0); }
      else if (q == 1) { if (kt + 1 < NKT) STAGE_A(c ^ 1, kt + 1, 1); }
      else if (q == 2) { if (kt + 2 < NKT) STAGE_B(c, kt + 2, 0); }
      else             { if (kt + 2 < NKT) STAGE_B(c, kt + 2, 1); }
      __builtin_amdgcn_s_barrier();
      asm volatile("s_waitcnt lgkmcnt(0)" ::: "memory");
      __builtin_amdgcn_s_setprio(1);
#pragma unroll
      for (int fn = 0; fn < 4; ++fn) {
        acc[2 * q][fn]     = __builtin_amdgcn_mfma_f32_16x16x32_bf16(a00, b0[fn], acc[2 * q][fn], 0, 0, 0);
        acc[2 * q][fn]     = __builtin_amdgcn_mfma_f32_16x16x32_bf16(a01, b1[fn], acc[2 * q][fn], 0, 0, 0);
        acc[2 * q + 1][fn] = __builtin_amdgcn_mfma_f32_16x16x32_bf16(a10, b0[fn], acc[2 * q + 1][fn], 0, 0, 0);
        acc[2 * q + 1][fn] = __builtin_amdgcn_mfma_f32_16x16x32_bf16(a11, b1[fn], acc[2 * q + 1][fn], 0, 0, 0);
      }
      __builtin_amdgcn_s_setprio(0);
      if (q == 3) {
        if (kt < NKT - 2)        asm volatile("s_waitcnt vmcnt(4)" ::: "memory");
        else if (kt == NKT - 2)  asm volatile("s_waitcnt vmcnt(0)" ::: "memory");
      }
      __builtin_amdgcn_s_barrier();
    }
  }
#undef STAGE_A
#undef STAGE_B

  // epilogue: bias + relu + gated expert-sum + direct towers write.
  // lane col n(fn) = wn*64+fn*16+lr -> e = 2*fn+hi, h = hs*32+wn*8+(lr&7)
  int hi = lr >> 3, h7 = lr & 7;
  int hglob = hs * 32 + wn * 8 + h7;
  float bev[4];
#pragma unroll
  for (int fn = 0; fn < 4; ++fn)
    bev[fn] = be[(2 * fn + hi) * H_DIM + hglob];
#pragma unroll
  for (int fm = 0; fm < 8; ++fm) {
    int r0 = m0 + wm * 128 + fm * 16 + lq * 4;
    float vv[4][4];
#pragma unroll
    for (int fn = 0; fn < 4; ++fn)
#pragma unroll
      for (int j = 0; j < 4; ++j)
        vv[fn][j] = fmaxf(acc[fm][fn][j] + bev[fn], 0.f);
#pragma unroll
    for (int tk = 0; tk < 4; ++tk) {
      float4 gv[4];
#pragma unroll
      for (int fn = 0; fn < 4; ++fn)
        gv[fn] = *(const float4*)(Gt + (size_t)(tk * 8 + 2 * fn + hi) * B_ROWS + r0);
      float s0 = gv[0].x * vv[0][0] + gv[1].x * vv[1][0] + gv[2].x * vv[2][0] + gv[3].x * vv[3][0];
      float s1 = gv[0].y * vv[0][1] + gv[1].y * vv[1][1] + gv[2].y * vv[2][1] + gv[3].y * vv[3][1];
      float s2 = gv[0].z * vv[0][2] + gv[1].z * vv[1][2] + gv[2].z * vv[2][2] + gv[3].z * vv[3][2];
      float s3 = gv[0].w * vv[0][3] + gv[1].w * vv[1][3] + gv[2].w * vv[2][3] + gv[3].w * vv[3][3];
      s0 += __shfl_xor(s0, 8);
      s1 += __shfl_xor(s1, 8);
      s2 += __shfl_xor(s2, 8);
      s3 += __shfl_xor(s3, 8);
      if ((tk >> 1) == hi) {
        float* o = out + ((size_t)tk * B_ROWS + r0) * H_DIM + hglob;
        o[0]                 = s0;
        o[(size_t)H_DIM]     = s1;
        o[(size_t)H_DIM * 2] = s2;
        o[(size_t)H_DIM * 3] = s3;
      }
    }
  }
}

extern "C" void kernel_launch(void* const* d_in, const int* in_sizes, int n_in,
                              void* d_out, int out_size, void* d_ws, size_t ws_size,
                              hipStream_t stream) {
  const float* x  = (const float*)d_in[0];
  const float* We = (const float*)d_in[1];
  const float* be = (const float*)d_in[2];
  const float* Wg = (const float*)d_in[3];
  const float* bg = (const float*)d_in[4];
  float* out = (float*)d_out;
  char* ws = (char*)d_ws;
  unsigned short* x_b  = (unsigned short*)(ws + WS_XB);
  unsigned short* We_t = (unsigned short*)(ws + WS_WET);
  unsigned short* Wg_t = (unsigned short*)(ws + WS_WGT);
  float*          Gt   = (float*)(ws + WS_GT);

  k_prep_w<<<544 + 8192, 256, 0, stream>>>(x, We, Wg, x_b, We_t, Wg_t);
  k_gates<<<B_ROWS / 64, 256, 0, stream>>>(x_b, Wg_t, bg, Gt);
  k_expert<<<512, 512, 0, stream>>>(x_b, We_t, be, Gt, out);
}